// Round 3
// baseline (203.937 us; speedup 1.0000x reference)
//
#include <hip/hip_runtime.h>
#include <hip/hip_bf16.h>

// Problem constants
#define BB 8
#define TT 2048
#define EE 1024
#define HH 64

typedef __attribute__((ext_vector_type(8))) short short8;
typedef __attribute__((ext_vector_type(4))) float f32x4;

__device__ inline f32x4 mfma_16x16x32(short8 a, short8 b, f32x4 c) {
  return __builtin_amdgcn_mfma_f32_16x16x32_bf16(a, b, c, 0, 0, 0);
}

// async global->LDS, 16B per lane, LDS dest = wave-uniform base + lane*16
__device__ inline void gload_lds16(const __hip_bfloat16* g, __hip_bfloat16* l) {
  __builtin_amdgcn_global_load_lds((const __attribute__((address_space(1))) void*)g,
                                   (__attribute__((address_space(3))) void*)l,
                                   16, 0, 0);
}

__device__ inline short f2bf(float f) {
  __hip_bfloat16 h = __float2bfloat16(f);
  return *reinterpret_cast<short*>(&h);
}
__device__ inline float bf2f(short s) {
  __hip_bfloat16 h = *reinterpret_cast<__hip_bfloat16*>(&s);
  return __bfloat162float(h);
}

// ---------------------------------------------------------------------------
// Kernel 0: split-precision transposed weights.
// Wthi/Wtlo[n][e]: hi = bf16(W), lo = bf16(W - hi). n in [0,192), e in [0,1024).
// ---------------------------------------------------------------------------
__global__ void prep_w(const float* __restrict__ Wq, const float* __restrict__ Wk,
                       const float* __restrict__ Wv,
                       __hip_bfloat16* __restrict__ Wthi,
                       __hip_bfloat16* __restrict__ Wtlo) {
  const int n = blockIdx.x;          // 0..191
  const int m = n >> 6;
  const int h = n & 63;
  const float* W = (m == 0) ? Wq : (m == 1) ? Wk : Wv;
  const int e0 = threadIdx.x * 4;    // 256 threads * 4 = 1024
#pragma unroll
  for (int j = 0; j < 4; ++j) {
    const float w = W[(e0 + j) * 64 + h];
    const __hip_bfloat16 hi = __float2bfloat16(w);
    Wthi[n * 1024 + e0 + j] = hi;
    Wtlo[n * 1024 + e0 + j] = __float2bfloat16(w - __bfloat162float(hi));
  }
}

// ---------------------------------------------------------------------------
// Kernel A (unchanged this round): split-bf16 fp32-emulated GEMM.
// q|k|v = x @ [Wq|Wk|Wv]. M=16384, K=1024, N=192. 256 blocks x 64 rows.
// acc = xh*wh + xh*wl + xl*wh (lo*lo dropped).
// Outputs: qhi/qlo, khi/klo [t][h] bf16 pairs; vT[b][h][t] single bf16.
// ---------------------------------------------------------------------------
__global__ __launch_bounds__(256) void qkv_gemm(
    const float* __restrict__ x,
    const __hip_bfloat16* __restrict__ Wthi, const __hip_bfloat16* __restrict__ Wtlo,
    __hip_bfloat16* __restrict__ qhi, __hip_bfloat16* __restrict__ qlo,
    __hip_bfloat16* __restrict__ khi, __hip_bfloat16* __restrict__ klo,
    __hip_bfloat16* __restrict__ vT) {
  __shared__ __hip_bfloat16 Ahi[2][64 * 72];    // 64 rows x 64 k, pad to 72
  __shared__ __hip_bfloat16 Alo[2][64 * 72];
  __shared__ __hip_bfloat16 Bhi[2][192 * 64];   // 192 n-rows x 64 k, swizzled
  __shared__ __hip_bfloat16 Blo[2][192 * 64];

  const int tid  = threadIdx.x;
  const int wave = tid >> 6;
  const int lane = tid & 63;
  const int row0 = blockIdx.x * 64;

  const int lr = tid >> 2;           // 0..63 local row
  const int le = (tid & 3) * 16;     // 0/16/32/48 within 64-wide k-chunk
  const float* xrow = x + (row0 + lr) * 1024 + le;

  f32x4 acc[12];
#pragma unroll
  for (int j = 0; j < 12; ++j) acc[j] = f32x4{0.f, 0.f, 0.f, 0.f};

  const int l15 = lane & 15, l4 = lane >> 4;

  auto issue_B = [&](int c, int buf) {
    const int g = (lane & 7) ^ ((lane >> 3) & 7);
#pragma unroll
    for (int s = 0; s < 6; ++s) {
      const int qq = wave * 6 + s;                   // 0..23 (8 n-rows each)
      const int n  = qq * 8 + (lane >> 3);
      gload_lds16(Wthi + n * 1024 + c * 64 + g * 8, &Bhi[buf][qq * 512]);
      gload_lds16(Wtlo + n * 1024 + c * 64 + g * 8, &Blo[buf][qq * 512]);
    }
  };
  auto write_A = [&](int buf, const f32x4* xr) {
    short8 h0, h1, l0, l1;
    const float* xf = (const float*)xr;
#pragma unroll
    for (int j = 0; j < 8; ++j) {
      const float v = xf[j];
      const short h = f2bf(v);
      h0[j] = h;
      l0[j] = f2bf(v - bf2f(h));
    }
#pragma unroll
    for (int j = 0; j < 8; ++j) {
      const float v = xf[8 + j];
      const short h = f2bf(v);
      h1[j] = h;
      l1[j] = f2bf(v - bf2f(h));
    }
    *(short8*)&Ahi[buf][lr * 72 + le]     = h0;
    *(short8*)&Ahi[buf][lr * 72 + le + 8] = h1;
    *(short8*)&Alo[buf][lr * 72 + le]     = l0;
    *(short8*)&Alo[buf][lr * 72 + le + 8] = l1;
  };
  auto compute = [&](int buf) {
    const int tr = wave * 16 + l15;
    short8 ah0 = *(const short8*)&Ahi[buf][tr * 72 + l4 * 8];
    short8 ah1 = *(const short8*)&Ahi[buf][tr * 72 + 32 + l4 * 8];
    short8 al0 = *(const short8*)&Alo[buf][tr * 72 + l4 * 8];
    short8 al1 = *(const short8*)&Alo[buf][tr * 72 + 32 + l4 * 8];
#pragma unroll
    for (int j = 0; j < 12; ++j) {
      const int n  = j * 16 + l15;
      const int o0 = ((l4)     ^ (n & 7)) * 8;
      const int o1 = ((4 + l4) ^ (n & 7)) * 8;
      short8 bh0 = *(const short8*)&Bhi[buf][n * 64 + o0];
      short8 bh1 = *(const short8*)&Bhi[buf][n * 64 + o1];
      short8 bl0 = *(const short8*)&Blo[buf][n * 64 + o0];
      short8 bl1 = *(const short8*)&Blo[buf][n * 64 + o1];
      acc[j] = mfma_16x16x32(ah0, bh0, acc[j]);
      acc[j] = mfma_16x16x32(ah1, bh1, acc[j]);
      acc[j] = mfma_16x16x32(ah0, bl0, acc[j]);
      acc[j] = mfma_16x16x32(ah1, bl1, acc[j]);
      acc[j] = mfma_16x16x32(al0, bh0, acc[j]);
      acc[j] = mfma_16x16x32(al1, bh1, acc[j]);
    }
  };

  f32x4 xr[4], xn[4];
  {
    const f32x4* p = (const f32x4*)xrow;
    xr[0] = p[0]; xr[1] = p[1]; xr[2] = p[2]; xr[3] = p[3];
  }
  issue_B(0, 0);
  __builtin_amdgcn_s_waitcnt(0);
  write_A(0, xr);
  __syncthreads();

  for (int c = 0; c < 16; ++c) {
    const int p = c & 1;
    if (c < 15) {
      const f32x4* pp = (const f32x4*)(xrow + (c + 1) * 64);
      xn[0] = pp[0]; xn[1] = pp[1]; xn[2] = pp[2]; xn[3] = pp[3];
      issue_B(c + 1, p ^ 1);
    }
    compute(p);
    if (c < 15) {
      __builtin_amdgcn_s_waitcnt(0);
      write_A(p ^ 1, xn);
    }
    __syncthreads();
  }

  const int strip = wave * 16;
#pragma unroll
  for (int j = 0; j < 12; ++j) {
    const int n  = j * 16 + l15;
    const int mm = n >> 6;     // 0=q,1=k,2=v (uniform per j)
    const int h  = n & 63;
#pragma unroll
    for (int r = 0; r < 4; ++r) {
      const int trow = row0 + strip + l4 * 4 + r;
      const float val = acc[j][r];
      const __hip_bfloat16 hi = __float2bfloat16(val);
      const __hip_bfloat16 lo = __float2bfloat16(val - __bfloat162float(hi));
      if (mm == 0) {
        qhi[trow * 64 + h] = hi;
        qlo[trow * 64 + h] = lo;
      } else if (mm == 1) {
        khi[trow * 64 + h] = hi;
        klo[trow * 64 + h] = lo;
      } else {
        const int bb = trow >> 11, tl = trow & 2047;
        vT[(bb * 64 + h) * 2048 + tl] = hi;
      }
    }
  }
}

// ---------------------------------------------------------------------------
// Kernel B v2: split-K flash attention. One block (4 waves) per (b, strip);
// the causal K-tile range is partitioned contiguously across the 4 waves;
// partial (m, l, O) merged through LDS. K/V B-fragments are loaded DIRECTLY
// from global into registers (no LDS staging); LDS holds only the per-wave
// P transpose buffer + merge buffers. Split-bf16 QK^T (fp32-accurate scores).
// ---------------------------------------------------------------------------
__global__ __launch_bounds__(256) void attn(
    const __hip_bfloat16* __restrict__ qhi, const __hip_bfloat16* __restrict__ qlo,
    const __hip_bfloat16* __restrict__ khi, const __hip_bfloat16* __restrict__ klo,
    const __hip_bfloat16* __restrict__ vT, float* __restrict__ out) {
  __shared__ __hip_bfloat16 Psm[4][16 * 72];   // per-wave P buffer, padded
  __shared__ float Osm[4][16][64];             // per-wave partial O
  __shared__ float Msm[4][16];                 // per-wave row max
  __shared__ float Lsm[4][16];                 // per-wave row sum

  const int tid   = threadIdx.x;
  const int wave  = tid >> 6;
  const int lane  = tid & 63;
  const int bid   = blockIdx.x;
  const int b     = bid >> 7;
  const int strip = 127 - (bid & 127);      // big-work blocks first
  const int t0    = strip * 16;
  const int l15 = lane & 15, l4 = lane >> 4;

  // causal K-tile range for this strip, split across 4 waves
  const int kt_total = (strip >> 2) + 1;           // tiles of 64 keys
  const int chunk    = (kt_total + 3) >> 2;
  const int ktb      = wave * chunk;
  const int kte      = min(ktb + chunk, kt_total);

  // Q A-frags (A[m=lane&15][k=quad*8+j]), hi+lo, in regs for all K-tiles
  const __hip_bfloat16* qph = qhi + (b * 2048 + t0 + l15) * 64;
  const __hip_bfloat16* qpl = qlo + (b * 2048 + t0 + l15) * 64;
  short8 qh0 = *(const short8*)(qph + l4 * 8);
  short8 qh1 = *(const short8*)(qph + 32 + l4 * 8);
  short8 ql0 = *(const short8*)(qpl + l4 * 8);
  short8 ql1 = *(const short8*)(qpl + 32 + l4 * 8);

  f32x4 acc[4];
#pragma unroll
  for (int j = 0; j < 4; ++j) acc[j] = f32x4{0.f, 0.f, 0.f, 0.f};
  float m_[4] = {-1e30f, -1e30f, -1e30f, -1e30f};
  float l_[4] = {0.f, 0.f, 0.f, 0.f};

  const __hip_bfloat16* kbase_h = khi + (size_t)b * 2048 * 64;
  const __hip_bfloat16* kbase_l = klo + (size_t)b * 2048 * 64;
  const __hip_bfloat16* vbase   = vT + (size_t)b * 64 * 2048;

  for (int kt = ktb; kt < kte; ++kt) {
    const int k0 = kt << 6;

    // ---- S = Q K^T (split precision): B-frags direct from global ----
    f32x4 s[4];
#pragma unroll
    for (int j = 0; j < 4; ++j) {
      const int key = k0 + j * 16 + l15;
      const __hip_bfloat16* kph = kbase_h + key * 64;
      const __hip_bfloat16* kpl = kbase_l + key * 64;
      short8 kh0 = *(const short8*)(kph + l4 * 8);
      short8 kh1 = *(const short8*)(kph + 32 + l4 * 8);
      short8 kl0 = *(const short8*)(kpl + l4 * 8);
      short8 kl1 = *(const short8*)(kpl + 32 + l4 * 8);
      f32x4 z = f32x4{0.f, 0.f, 0.f, 0.f};
      z = mfma_16x16x32(qh0, kh0, z);
      z = mfma_16x16x32(qh1, kh1, z);
      z = mfma_16x16x32(qh0, kl0, z);
      z = mfma_16x16x32(qh1, kl1, z);
      z = mfma_16x16x32(ql0, kh0, z);
      z = mfma_16x16x32(ql1, kh1, z);
      s[j] = z;
    }

    // ---- causal mask (only the tile touching the diagonal) ----
    if (k0 + 63 > t0) {
#pragma unroll
      for (int j = 0; j < 4; ++j) {
        const int key = k0 + j * 16 + l15;
#pragma unroll
        for (int r = 0; r < 4; ++r) {
          const int row = t0 + l4 * 4 + r;
          if (key > row) s[j][r] = -1e30f;
        }
      }
    }

    // ---- online softmax (4 rows/lane; reduce across 16-lane col groups) ----
    float mx[4], rs[4], al[4];
#pragma unroll
    for (int r = 0; r < 4; ++r)
      mx[r] = fmaxf(fmaxf(s[0][r], s[1][r]), fmaxf(s[2][r], s[3][r]));
    for (int off = 1; off < 16; off <<= 1) {
#pragma unroll
      for (int r = 0; r < 4; ++r) mx[r] = fmaxf(mx[r], __shfl_xor(mx[r], off));
    }
#pragma unroll
    for (int r = 0; r < 4; ++r) {
      const float mn = fmaxf(m_[r], mx[r]);
      al[r] = __expf(m_[r] - mn);
      m_[r] = mn;
      rs[r] = 0.f;
    }
#pragma unroll
    for (int j = 0; j < 4; ++j) {
#pragma unroll
      for (int r = 0; r < 4; ++r) {
        const float pv = __expf(s[j][r] - m_[r]);
        s[j][r] = pv;
        rs[r] += pv;
      }
    }
    for (int off = 1; off < 16; off <<= 1) {
#pragma unroll
      for (int r = 0; r < 4; ++r) rs[r] += __shfl_xor(rs[r], off);
    }
#pragma unroll
    for (int r = 0; r < 4; ++r) l_[r] = l_[r] * al[r] + rs[r];
#pragma unroll
    for (int j = 0; j < 4; ++j) {
#pragma unroll
      for (int r = 0; r < 4; ++r) acc[j][r] *= al[r];
    }

    // ---- issue V B-frag loads early (drained by the waitcnt below) ----
    short8 vf0[4], vf1[4];
#pragma unroll
    for (int j = 0; j < 4; ++j) {
      const int h = j * 16 + l15;
      const __hip_bfloat16* vp = vbase + h * 2048 + k0;
      vf0[j] = *(const short8*)(vp + l4 * 8);
      vf1[j] = *(const short8*)(vp + 32 + l4 * 8);
    }

    // ---- P: C-layout -> per-wave LDS -> A-layout ----
#pragma unroll
    for (int j = 0; j < 4; ++j) {
#pragma unroll
      for (int r = 0; r < 4; ++r)
        Psm[wave][(l4 * 4 + r) * 72 + j * 16 + l15] = __float2bfloat16(s[j][r]);
    }
    __builtin_amdgcn_s_waitcnt(0);   // LDS write->read visibility (same wave)
    short8 pf0 = *(const short8*)&Psm[wave][l15 * 72 + l4 * 8];
    short8 pf1 = *(const short8*)&Psm[wave][l15 * 72 + 32 + l4 * 8];

    // ---- O += P V ----
#pragma unroll
    for (int j = 0; j < 4; ++j) {
      acc[j] = mfma_16x16x32(pf0, vf0[j], acc[j]);
      acc[j] = mfma_16x16x32(pf1, vf1[j], acc[j]);
    }
  }

  // ---- write partials to LDS ----
#pragma unroll
  for (int j = 0; j < 4; ++j) {
#pragma unroll
    for (int r = 0; r < 4; ++r)
      Osm[wave][l4 * 4 + r][j * 16 + l15] = acc[j][r];
  }
  if (l15 == 0) {
#pragma unroll
    for (int r = 0; r < 4; ++r) {
      Msm[wave][l4 * 4 + r] = m_[r];
      Lsm[wave][l4 * 4 + r] = l_[r];
    }
  }
  __syncthreads();

  // ---- merge across waves: wave w handles rows [w*4, w*4+4), lane = h ----
#pragma unroll
  for (int rr = 0; rr < 4; ++rr) {
    const int row = wave * 4 + rr;
    float M = fmaxf(fmaxf(Msm[0][row], Msm[1][row]),
                    fmaxf(Msm[2][row], Msm[3][row]));
    float L = 0.f, O = 0.f;
#pragma unroll
    for (int w = 0; w < 4; ++w) {
      const float a = __expf(Msm[w][row] - M);
      L += Lsm[w][row] * a;
      O += Osm[w][row][lane] * a;
    }
    out[(b * 2048 + t0 + row) * 64 + lane] = O / L;
  }
}

// ---------------------------------------------------------------------------
extern "C" void kernel_launch(void* const* d_in, const int* in_sizes, int n_in,
                              void* d_out, int out_size, void* d_ws, size_t ws_size,
                              hipStream_t stream) {
  const float* x  = (const float*)d_in[0];
  const float* Wq = (const float*)d_in[1];
  const float* Wk = (const float*)d_in[2];
  const float* Wv = (const float*)d_in[3];
  float* out = (float*)d_out;

  char* ws = (char*)d_ws;
  __hip_bfloat16* Wthi = (__hip_bfloat16*)ws;                   // 384 KB
  __hip_bfloat16* Wtlo = (__hip_bfloat16*)(ws + 393216);        // 384 KB
  __hip_bfloat16* qhi  = (__hip_bfloat16*)(ws + 786432);        // 2 MB each
  __hip_bfloat16* qlo  = (__hip_bfloat16*)(ws + 786432 + 1 * 2097152);
  __hip_bfloat16* khi  = (__hip_bfloat16*)(ws + 786432 + 2 * 2097152);
  __hip_bfloat16* klo  = (__hip_bfloat16*)(ws + 786432 + 3 * 2097152);
  __hip_bfloat16* vT   = (__hip_bfloat16*)(ws + 786432 + 4 * 2097152);

  prep_w<<<192, 256, 0, stream>>>(Wq, Wk, Wv, Wthi, Wtlo);
  qkv_gemm<<<256, 256, 0, stream>>>(x, Wthi, Wtlo, qhi, qlo, khi, klo, vT);
  attn<<<BB * (TT / 16), 256, 0, stream>>>(qhi, qlo, khi, klo, vT, out);
}

// Round 4
// 172.234 us; speedup vs baseline: 1.1841x; 1.1841x over previous
//
#include <hip/hip_runtime.h>
#include <hip/hip_bf16.h>

// Problem constants
#define BB 8
#define TT 2048
#define EE 1024
#define HH 64

typedef __attribute__((ext_vector_type(8))) short short8;
typedef __attribute__((ext_vector_type(4))) float f32x4;

__device__ inline f32x4 mfma_16x16x32(short8 a, short8 b, f32x4 c) {
  return __builtin_amdgcn_mfma_f32_16x16x32_bf16(a, b, c, 0, 0, 0);
}

// async global->LDS, 16B per lane, LDS dest = wave-uniform base + lane*16
__device__ inline void gload_lds16(const __hip_bfloat16* g, __hip_bfloat16* l) {
  __builtin_amdgcn_global_load_lds((const __attribute__((address_space(1))) void*)g,
                                   (__attribute__((address_space(3))) void*)l,
                                   16, 0, 0);
}

__device__ inline short f2bf(float f) {
  __hip_bfloat16 h = __float2bfloat16(f);
  return *reinterpret_cast<short*>(&h);
}
__device__ inline float bf2f(short s) {
  __hip_bfloat16 h = *reinterpret_cast<__hip_bfloat16*>(&s);
  return __bfloat162float(h);
}

// ---------------------------------------------------------------------------
// Kernel 0: split-precision transposed weights.
// Wthi/Wtlo[n][e]: hi = bf16(W), lo = bf16(W - hi). n in [0,192), e in [0,1024).
// ---------------------------------------------------------------------------
__global__ void prep_w(const float* __restrict__ Wq, const float* __restrict__ Wk,
                       const float* __restrict__ Wv,
                       __hip_bfloat16* __restrict__ Wthi,
                       __hip_bfloat16* __restrict__ Wtlo) {
  const int n = blockIdx.x;          // 0..191
  const int m = n >> 6;
  const int h = n & 63;
  const float* W = (m == 0) ? Wq : (m == 1) ? Wk : Wv;
  const int e0 = threadIdx.x * 4;    // 256 threads * 4 = 1024
#pragma unroll
  for (int j = 0; j < 4; ++j) {
    const float w = W[(e0 + j) * 64 + h];
    const __hip_bfloat16 hi = __float2bfloat16(w);
    Wthi[n * 1024 + e0 + j] = hi;
    Wtlo[n * 1024 + e0 + j] = __float2bfloat16(w - __bfloat162float(hi));
  }
}

// ---------------------------------------------------------------------------
// Kernel A: split-bf16 fp32-emulated GEMM: q|k|v = x @ [Wq|Wk|Wv].
// v-columns (n>=128, j>=8) use hi-only (v precision doesn't need the
// lo-correction) -> 56 instead of 72 MFMAs/chunk, 1/3 less Blo traffic.
// Outputs: qhi/qlo, khi/klo [t][h] bf16 pairs; vT[b][h][t] single bf16.
// ---------------------------------------------------------------------------
__global__ __launch_bounds__(256) void qkv_gemm(
    const float* __restrict__ x,
    const __hip_bfloat16* __restrict__ Wthi, const __hip_bfloat16* __restrict__ Wtlo,
    __hip_bfloat16* __restrict__ qhi, __hip_bfloat16* __restrict__ qlo,
    __hip_bfloat16* __restrict__ khi, __hip_bfloat16* __restrict__ klo,
    __hip_bfloat16* __restrict__ vT) {
  __shared__ __hip_bfloat16 Ahi[2][64 * 72];    // 64 rows x 64 k, pad to 72
  __shared__ __hip_bfloat16 Alo[2][64 * 72];
  __shared__ __hip_bfloat16 Bhi[2][192 * 64];   // 192 n-rows x 64 k, swizzled
  __shared__ __hip_bfloat16 Blo[2][128 * 64];   // only q,k n-rows need lo

  const int tid  = threadIdx.x;
  const int wave = tid >> 6;
  const int lane = tid & 63;
  const int row0 = blockIdx.x * 64;

  const int lr = tid >> 2;           // 0..63 local row
  const int le = (tid & 3) * 16;     // 0/16/32/48 within 64-wide k-chunk
  const float* xrow = x + (row0 + lr) * 1024 + le;

  f32x4 acc[12];
#pragma unroll
  for (int j = 0; j < 12; ++j) acc[j] = f32x4{0.f, 0.f, 0.f, 0.f};

  const int l15 = lane & 15, l4 = lane >> 4;

  auto issue_B = [&](int c, int buf) {
    const int g = (lane & 7) ^ ((lane >> 3) & 7);
#pragma unroll
    for (int s = 0; s < 6; ++s) {
      const int qq = wave * 6 + s;                   // 0..23 (8 n-rows each)
      const int n  = qq * 8 + (lane >> 3);
      gload_lds16(Wthi + n * 1024 + c * 64 + g * 8, &Bhi[buf][qq * 512]);
      if (qq < 16)
        gload_lds16(Wtlo + n * 1024 + c * 64 + g * 8, &Blo[buf][qq * 512]);
    }
  };
  auto write_A = [&](int buf, const f32x4* xr) {
    short8 h0, h1, l0, l1;
    const float* xf = (const float*)xr;
#pragma unroll
    for (int j = 0; j < 8; ++j) {
      const float v = xf[j];
      const short h = f2bf(v);
      h0[j] = h;
      l0[j] = f2bf(v - bf2f(h));
    }
#pragma unroll
    for (int j = 0; j < 8; ++j) {
      const float v = xf[8 + j];
      const short h = f2bf(v);
      h1[j] = h;
      l1[j] = f2bf(v - bf2f(h));
    }
    *(short8*)&Ahi[buf][lr * 72 + le]     = h0;
    *(short8*)&Ahi[buf][lr * 72 + le + 8] = h1;
    *(short8*)&Alo[buf][lr * 72 + le]     = l0;
    *(short8*)&Alo[buf][lr * 72 + le + 8] = l1;
  };
  auto compute = [&](int buf) {
    const int tr = wave * 16 + l15;
    short8 ah0 = *(const short8*)&Ahi[buf][tr * 72 + l4 * 8];
    short8 ah1 = *(const short8*)&Ahi[buf][tr * 72 + 32 + l4 * 8];
    short8 al0 = *(const short8*)&Alo[buf][tr * 72 + l4 * 8];
    short8 al1 = *(const short8*)&Alo[buf][tr * 72 + 32 + l4 * 8];
#pragma unroll
    for (int j = 0; j < 12; ++j) {
      const int n  = j * 16 + l15;
      const int o0 = ((l4)     ^ (n & 7)) * 8;
      const int o1 = ((4 + l4) ^ (n & 7)) * 8;
      short8 bh0 = *(const short8*)&Bhi[buf][n * 64 + o0];
      short8 bh1 = *(const short8*)&Bhi[buf][n * 64 + o1];
      acc[j] = mfma_16x16x32(ah0, bh0, acc[j]);
      acc[j] = mfma_16x16x32(ah1, bh1, acc[j]);
      if (j < 8) {   // q,k need the lo-correction; v doesn't
        short8 bl0 = *(const short8*)&Blo[buf][n * 64 + o0];
        short8 bl1 = *(const short8*)&Blo[buf][n * 64 + o1];
        acc[j] = mfma_16x16x32(ah0, bl0, acc[j]);
        acc[j] = mfma_16x16x32(ah1, bl1, acc[j]);
        acc[j] = mfma_16x16x32(al0, bh0, acc[j]);
        acc[j] = mfma_16x16x32(al1, bh1, acc[j]);
      }
    }
  };

  f32x4 xr[4], xn[4];
  {
    const f32x4* p = (const f32x4*)xrow;
    xr[0] = p[0]; xr[1] = p[1]; xr[2] = p[2]; xr[3] = p[3];
  }
  issue_B(0, 0);
  __builtin_amdgcn_s_waitcnt(0);
  write_A(0, xr);
  __syncthreads();

  for (int c = 0; c < 16; ++c) {
    const int p = c & 1;
    if (c < 15) {
      const f32x4* pp = (const f32x4*)(xrow + (c + 1) * 64);
      xn[0] = pp[0]; xn[1] = pp[1]; xn[2] = pp[2]; xn[3] = pp[3];
      issue_B(c + 1, p ^ 1);
    }
    compute(p);
    if (c < 15) {
      __builtin_amdgcn_s_waitcnt(0);
      write_A(p ^ 1, xn);
    }
    __syncthreads();
  }

  const int strip = wave * 16;
#pragma unroll
  for (int j = 0; j < 12; ++j) {
    const int n  = j * 16 + l15;
    const int mm = n >> 6;     // 0=q,1=k,2=v (uniform per j)
    const int h  = n & 63;
#pragma unroll
    for (int r = 0; r < 4; ++r) {
      const int trow = row0 + strip + l4 * 4 + r;
      const float val = acc[j][r];
      const __hip_bfloat16 hi = __float2bfloat16(val);
      const __hip_bfloat16 lo = __float2bfloat16(val - __bfloat162float(hi));
      if (mm == 0) {
        qhi[trow * 64 + h] = hi;
        qlo[trow * 64 + h] = lo;
      } else if (mm == 1) {
        khi[trow * 64 + h] = hi;
        klo[trow * 64 + h] = lo;
      } else {
        const int bb = trow >> 11, tl = trow & 2047;
        vT[(bb * 64 + h) * 2048 + tl] = hi;
      }
    }
  }
}

// ---------------------------------------------------------------------------
// Kernel B v3: flash attention, 64 Q-rows PER WAVE (4 MFMA sub-tiles), 4-way
// split-K within a 4-wave block, no barriers in the K-loop, LDS merge at end.
// Grid = 256 blocks = 8 batches x 32 strips with b = bid&7 so each batch's
// blocks land on one XCD (per-batch K/V = 768 KB fits its 4MB L2 -> K/V
// re-reads become XCD-local). Traffic: 405 MB -> ~101 MB total, L2-rate.
// ---------------------------------------------------------------------------
__global__ __launch_bounds__(256, 1) void attn(
    const __hip_bfloat16* __restrict__ qhi, const __hip_bfloat16* __restrict__ qlo,
    const __hip_bfloat16* __restrict__ khi, const __hip_bfloat16* __restrict__ klo,
    const __hip_bfloat16* __restrict__ vT, float* __restrict__ out) {
  __shared__ __hip_bfloat16 Psm[4][64 * 72];   // per-wave P (64 rows), padded
  __shared__ float Osm[4][64][65];             // per-wave partial O, padded
  __shared__ float Msm[4][64];                 // per-wave row max
  __shared__ float Lsm[4][64];                 // per-wave row sum

  const int tid   = threadIdx.x;
  const int wave  = tid >> 6;
  const int lane  = tid & 63;
  const int bid   = blockIdx.x;
  const int b     = bid & 7;               // XCD-local batch assignment
  const int strip = 31 - (bid >> 3);       // big-work strips dispatch first
  const int t0    = strip * 64;
  const int l15 = lane & 15, l4 = lane >> 4;

  // causal K-tile range for this 64-row strip, split across 4 waves
  const int kt_total = strip + 1;          // tiles of 64 keys
  const int chunk    = (kt_total + 3) >> 2;
  const int ktb      = wave * chunk;
  const int kte      = min(ktb + chunk, kt_total);

  // Q A-frags for 4 sub-tiles (rows t0+m*16..), hi+lo, in regs throughout
  short8 qh0[4], qh1[4], ql0[4], ql1[4];
#pragma unroll
  for (int m = 0; m < 4; ++m) {
    const __hip_bfloat16* qph = qhi + (b * 2048 + t0 + m * 16 + l15) * 64;
    const __hip_bfloat16* qpl = qlo + (b * 2048 + t0 + m * 16 + l15) * 64;
    qh0[m] = *(const short8*)(qph + l4 * 8);
    qh1[m] = *(const short8*)(qph + 32 + l4 * 8);
    ql0[m] = *(const short8*)(qpl + l4 * 8);
    ql1[m] = *(const short8*)(qpl + 32 + l4 * 8);
  }

  f32x4 acc[4][4];   // [m][j=h-group]
#pragma unroll
  for (int m = 0; m < 4; ++m)
#pragma unroll
    for (int j = 0; j < 4; ++j) acc[m][j] = f32x4{0.f, 0.f, 0.f, 0.f};
  float m_[4][4], l_[4][4];   // [m][r]
#pragma unroll
  for (int m = 0; m < 4; ++m)
#pragma unroll
    for (int r = 0; r < 4; ++r) { m_[m][r] = -1e30f; l_[m][r] = 0.f; }

  const __hip_bfloat16* kbase_h = khi + (size_t)b * 2048 * 64;
  const __hip_bfloat16* kbase_l = klo + (size_t)b * 2048 * 64;
  const __hip_bfloat16* vbase   = vT + (size_t)b * 64 * 2048;

  for (int kt = ktb; kt < kte; ++kt) {
    const int k0 = kt << 6;
    const bool diag = (k0 == t0);   // only the last tile touches the diagonal

    // ---- K frags (shared across the 4 Q sub-tiles) ----
    short8 kh0[4], kh1[4], kl0[4], kl1[4];
#pragma unroll
    for (int j = 0; j < 4; ++j) {
      const __hip_bfloat16* kph = kbase_h + (k0 + j * 16 + l15) * 64;
      const __hip_bfloat16* kpl = kbase_l + (k0 + j * 16 + l15) * 64;
      kh0[j] = *(const short8*)(kph + l4 * 8);
      kh1[j] = *(const short8*)(kph + 32 + l4 * 8);
      kl0[j] = *(const short8*)(kpl + l4 * 8);
      kl1[j] = *(const short8*)(kpl + 32 + l4 * 8);
    }

    // ---- per sub-tile: S, mask, online softmax, P->LDS ----
#pragma unroll
    for (int m = 0; m < 4; ++m) {
      f32x4 s[4];
#pragma unroll
      for (int j = 0; j < 4; ++j) {
        if (diag && j > m) {   // fully-masked sub-block: skip the MFMAs
          s[j] = f32x4{-1e30f, -1e30f, -1e30f, -1e30f};
          continue;
        }
        f32x4 z = f32x4{0.f, 0.f, 0.f, 0.f};
        z = mfma_16x16x32(qh0[m], kh0[j], z);
        z = mfma_16x16x32(qh1[m], kh1[j], z);
        z = mfma_16x16x32(qh0[m], kl0[j], z);
        z = mfma_16x16x32(qh1[m], kl1[j], z);
        z = mfma_16x16x32(ql0[m], kh0[j], z);
        z = mfma_16x16x32(ql1[m], kh1[j], z);
        s[j] = z;
      }
      if (diag) {   // partial mask on the j == m sub-block
#pragma unroll
        for (int j = 0; j < 4; ++j) {
          if (j != m) continue;
          const int key = j * 16 + l15;
#pragma unroll
          for (int r = 0; r < 4; ++r) {
            const int row = m * 16 + l4 * 4 + r;
            if (key > row) s[j][r] = -1e30f;
          }
        }
      }

      // online softmax for sub-tile m (reduce across 16-lane col groups)
      float mx[4], rs[4], al[4];
#pragma unroll
      for (int r = 0; r < 4; ++r)
        mx[r] = fmaxf(fmaxf(s[0][r], s[1][r]), fmaxf(s[2][r], s[3][r]));
      for (int off = 1; off < 16; off <<= 1) {
#pragma unroll
        for (int r = 0; r < 4; ++r) mx[r] = fmaxf(mx[r], __shfl_xor(mx[r], off));
      }
#pragma unroll
      for (int r = 0; r < 4; ++r) {
        const float mn = fmaxf(m_[m][r], mx[r]);
        al[r] = __expf(m_[m][r] - mn);
        m_[m][r] = mn;
        rs[r] = 0.f;
      }
#pragma unroll
      for (int j = 0; j < 4; ++j) {
#pragma unroll
        for (int r = 0; r < 4; ++r) {
          const float pv = __expf(s[j][r] - m_[m][r]);
          s[j][r] = pv;
          rs[r] += pv;
        }
      }
      for (int off = 1; off < 16; off <<= 1) {
#pragma unroll
        for (int r = 0; r < 4; ++r) rs[r] += __shfl_xor(rs[r], off);
      }
#pragma unroll
      for (int r = 0; r < 4; ++r) l_[m][r] = l_[m][r] * al[r] + rs[r];
#pragma unroll
      for (int j = 0; j < 4; ++j)
#pragma unroll
        for (int r = 0; r < 4; ++r) acc[m][j][r] *= al[r];

      // P (C-layout) -> per-wave LDS rows m*16..
#pragma unroll
      for (int j = 0; j < 4; ++j)
#pragma unroll
        for (int r = 0; r < 4; ++r)
          Psm[wave][(m * 16 + l4 * 4 + r) * 72 + j * 16 + l15] =
              __float2bfloat16(s[j][r]);
    }

    // ---- V frags (shared across sub-tiles) ----
    short8 vf0[4], vf1[4];
#pragma unroll
    for (int j = 0; j < 4; ++j) {
      const __hip_bfloat16* vp = vbase + (j * 16 + l15) * 2048 + k0;
      vf0[j] = *(const short8*)(vp + l4 * 8);
      vf1[j] = *(const short8*)(vp + 32 + l4 * 8);
    }

    __builtin_amdgcn_s_waitcnt(0);   // P LDS write->read + V loads drained

    // ---- O += P V for each sub-tile ----
#pragma unroll
    for (int m = 0; m < 4; ++m) {
      short8 pf0 = *(const short8*)&Psm[wave][(m * 16 + l15) * 72 + l4 * 8];
      short8 pf1 = *(const short8*)&Psm[wave][(m * 16 + l15) * 72 + 32 + l4 * 8];
#pragma unroll
      for (int j = 0; j < 4; ++j) {
        acc[m][j] = mfma_16x16x32(pf0, vf0[j], acc[m][j]);
        acc[m][j] = mfma_16x16x32(pf1, vf1[j], acc[m][j]);
      }
    }
  }

  // ---- write partials to LDS ----
#pragma unroll
  for (int m = 0; m < 4; ++m) {
#pragma unroll
    for (int j = 0; j < 4; ++j)
#pragma unroll
      for (int r = 0; r < 4; ++r)
        Osm[wave][m * 16 + l4 * 4 + r][j * 16 + l15] = acc[m][j][r];
    if (l15 == 0) {
#pragma unroll
      for (int r = 0; r < 4; ++r) {
        Msm[wave][m * 16 + l4 * 4 + r] = m_[m][r];
        Lsm[wave][m * 16 + l4 * 4 + r] = l_[m][r];
      }
    }
  }
  __syncthreads();

  // ---- merge across waves: wave w merges rows [w*16, w*16+16), lane = h ----
#pragma unroll
  for (int rr = 0; rr < 16; ++rr) {
    const int row = wave * 16 + rr;
    float M = fmaxf(fmaxf(Msm[0][row], Msm[1][row]),
                    fmaxf(Msm[2][row], Msm[3][row]));
    float L = 0.f, O = 0.f;
#pragma unroll
    for (int w = 0; w < 4; ++w) {
      const float a = __expf(Msm[w][row] - M);
      L += Lsm[w][row] * a;
      O += Osm[w][row][lane] * a;
    }
    out[(b * 2048 + t0 + row) * 64 + lane] = O / L;
  }
}

// ---------------------------------------------------------------------------
extern "C" void kernel_launch(void* const* d_in, const int* in_sizes, int n_in,
                              void* d_out, int out_size, void* d_ws, size_t ws_size,
                              hipStream_t stream) {
  const float* x  = (const float*)d_in[0];
  const float* Wq = (const float*)d_in[1];
  const float* Wk = (const float*)d_in[2];
  const float* Wv = (const float*)d_in[3];
  float* out = (float*)d_out;

  char* ws = (char*)d_ws;
  __hip_bfloat16* Wthi = (__hip_bfloat16*)ws;                   // 384 KB
  __hip_bfloat16* Wtlo = (__hip_bfloat16*)(ws + 393216);        // 384 KB
  __hip_bfloat16* qhi  = (__hip_bfloat16*)(ws + 786432);        // 2 MB each
  __hip_bfloat16* qlo  = (__hip_bfloat16*)(ws + 786432 + 1 * 2097152);
  __hip_bfloat16* khi  = (__hip_bfloat16*)(ws + 786432 + 2 * 2097152);
  __hip_bfloat16* klo  = (__hip_bfloat16*)(ws + 786432 + 3 * 2097152);
  __hip_bfloat16* vT   = (__hip_bfloat16*)(ws + 786432 + 4 * 2097152);

  prep_w<<<192, 256, 0, stream>>>(Wq, Wk, Wv, Wthi, Wtlo);
  qkv_gemm<<<256, 256, 0, stream>>>(x, Wthi, Wtlo, qhi, qlo, khi, klo, vT);
  attn<<<256, 256, 0, stream>>>(qhi, qlo, khi, klo, vT, out);
}